// Round 10
// baseline (87.181 us; speedup 1.0000x reference)
//
#include <hip/hip_runtime.h>
#include <math.h>

#define B_SZ 1024
#define C_SZ 1000
#define H_SZ 512

// ws layout (bytes):
//   [0, 65536)  float part[16][1024]  per-bx-strip row maxes (agent-scope atomics)

typedef __attribute__((ext_vector_type(8))) short bf16x8;
typedef __attribute__((ext_vector_type(4))) float f32x4;

#define KC 128          // k floats per chunk
#define RS 136          // LDS row stride in shorts (+8 pad)

// fp32x8 -> bf16x8 (RNE)
__device__ __forceinline__ uint4 pack8(float4 a, float4 b) {
    unsigned e[8] = {__float_as_uint(a.x), __float_as_uint(a.y),
                     __float_as_uint(a.z), __float_as_uint(a.w),
                     __float_as_uint(b.x), __float_as_uint(b.y),
                     __float_as_uint(b.z), __float_as_uint(b.w)};
    unsigned short h[8];
#pragma unroll
    for (int i = 0; i < 8; ++i) {
        unsigned v = e[i];
        v += 0x7fffu + ((v >> 16) & 1u);
        h[i] = (unsigned short)(v >> 16);
    }
    uint4 p;
    p.x = (unsigned)h[0] | ((unsigned)h[1] << 16);
    p.y = (unsigned)h[2] | ((unsigned)h[3] << 16);
    p.z = (unsigned)h[4] | ((unsigned)h[5] << 16);
    p.w = (unsigned)h[6] | ((unsigned)h[7] << 16);
    return p;
}

__device__ __forceinline__ float sumsq8(float4 a, float4 b) {
    return a.x * a.x + a.y * a.y + a.z * a.z + a.w * a.w +
           b.x * b.x + b.y * b.y + b.z * b.z + b.w * b.w;
}

// ---------------------------------------------------------------------------
// K1: self-contained gathered bf16 MFMA GEMM, 64(b) x 64(c) tiles,
// grid (16,16) = 256 blocks (1/CU). Per block: in-block argmax of its 64
// y-rows; A (64 gathered w-rows) + B (64 class w-rows) staged fp32->bf16
// in 4 K-chunks of 128; row norms accumulated in fp32 during staging.
// Wave wv: m-rows wv*16..+15 x all 4 c-subtiles (R5-verified mapping).
// No cross-kernel reads; part written with agent-scope atomic stores.
__global__ __launch_bounds__(256) void k_main(
    const float* __restrict__ y, const float* __restrict__ w,
    const float* __restrict__ eps_p, const float* __restrict__ lip_p,
    float* __restrict__ part) {
    __shared__ __align__(16) short As[64 * RS];
    __shared__ __align__(16) short Bs[64 * RS];
    __shared__ int sjv[64];
    __shared__ float sym[64];
    __shared__ float snj[64];
    __shared__ float snc[64];

    const int t = threadIdx.x;
    const int wv = t >> 6, lane = t & 63;
    const int col = lane & 15, quad = lane >> 4;
    const int bx = blockIdx.x, by = blockIdx.y;
    const int b0 = by * 64, c0 = bx * 64;

    // ---- Phase A: in-block argmax/max of the 64 y-rows (4 thr/row) -------
    {
        const int lr = t >> 2, seg = t & 3;
        const float* yrow = y + (b0 + lr) * C_SZ;
        float best = -INFINITY;
        int bidx = 0x7fffffff;
#pragma unroll
        for (int i = 0; i < 63; ++i) {
            const int idx = i * 4 + seg;  // float4 index; 250 cover the row
            if (idx < 250) {
                float4 v = *(const float4*)(yrow + idx * 4);
                float e[4] = {v.x, v.y, v.z, v.w};
#pragma unroll
                for (int j = 0; j < 4; ++j) {
                    if (e[j] > best) { best = e[j]; bidx = idx * 4 + j; }
                }
            }
        }
        // reduce across the 4 lanes of this row group (first index on ties)
#pragma unroll
        for (int off = 1; off < 4; off <<= 1) {
            float ov = __shfl_xor(best, off, 64);
            int oi = __shfl_xor(bidx, off, 64);
            if (ov > best || (ov == best && oi < bidx)) { best = ov; bidx = oi; }
        }
        if (seg == 0) { sjv[lr] = bidx; sym[lr] = best; }
    }
    __syncthreads();

    // ---- Staging setup: 2 threads per row (128 rows: 64 A then 64 B) -----
    const int srow = t >> 1;       // 0..127
    const int shalf = t & 1;       // half of each 128-float chunk
    const bool isA = srow < 64;
    const int lrow = isA ? srow : srow - 64;
    int grow;
    if (isA) {
        grow = sjv[lrow];
    } else {
        grow = c0 + lrow;
        if (grow > C_SZ - 1) grow = C_SZ - 1;
    }
    const float* gsrc = w + grow * H_SZ + shalf * 64;
    short* ldst = (isA ? &As[lrow * RS] : &Bs[lrow * RS]) + shalf * 64;

    const short* ard = &As[(wv * 16 + col) * RS + quad * 8];
    const short* brd = &Bs[col * RS + quad * 8];

    f32x4 acc[4] = {{0.f, 0.f, 0.f, 0.f},
                    {0.f, 0.f, 0.f, 0.f},
                    {0.f, 0.f, 0.f, 0.f},
                    {0.f, 0.f, 0.f, 0.f}};
    float nacc = 0.f;

    for (int ch = 0; ch < 4; ++ch) {
        // stage 64 floats (this thread's half-chunk) -> 8 x uint4 LDS writes
#pragma unroll
        for (int j = 0; j < 8; ++j) {
            float4 a = *(const float4*)(gsrc + ch * KC + j * 8);
            float4 b = *(const float4*)(gsrc + ch * KC + j * 8 + 4);
            nacc += sumsq8(a, b);
            *(uint4*)(ldst + j * 8) = pack8(a, b);
        }
        __syncthreads();
        // compute: 4 k-steps of 32, 4 c-subtiles each
#pragma unroll
        for (int ks = 0; ks < 4; ++ks) {
            bf16x8 af = *(const bf16x8*)(ard + ks * 32);
#pragma unroll
            for (int ct = 0; ct < 4; ++ct) {
                bf16x8 bf = *(const bf16x8*)(brd + ct * 16 * RS + ks * 32);
                acc[ct] = __builtin_amdgcn_mfma_f32_16x16x32_bf16(af, bf,
                                                                  acc[ct], 0, 0, 0);
            }
        }
        __syncthreads();
    }

    // ---- Row norms: combine the two half-sums (partner lane xor 1) -------
    nacc += __shfl_xor(nacc, 1, 64);
    if (shalf == 0) {
        if (isA) snj[lrow] = nacc;
        else snc[lrow] = nacc;
    }
    __syncthreads();

    // ---- Epilogue (R5-verified). C/D: col=lane&15, row=quad*4+reg --------
    const float eps = *eps_p;
    const float L = *lip_p;
    const float L2 = L * L;
    float rmax[4];
#pragma unroll
    for (int i = 0; i < 4; ++i) {
        const int br = wv * 16 + quad * 4 + i;
        const int b = b0 + br;
        const float nj = snj[br];
        const float ym = sym[br];
        float m = -INFINITY;
#pragma unroll
        for (int ct = 0; ct < 4; ++ct) {
            const int cc = c0 + ct * 16 + col;
            if (cc < C_SZ) {
                const float yv = y[b * C_SZ + cc];
                const float sq = L2 * (nj + snc[ct * 16 + col] - 2.0f * acc[ct][i]);
                const float K = sq > 0.f ? sqrtf(sq) : 0.f;
                const float cand = (yv == ym) ? -INFINITY : yv + eps * K;
                m = fmaxf(m, cand);
            }
        }
        rmax[i] = m;
    }
#pragma unroll
    for (int off = 8; off; off >>= 1)
#pragma unroll
        for (int i = 0; i < 4; ++i)
            rmax[i] = fmaxf(rmax[i], __shfl_xor(rmax[i], off, 64));
    if (col == 0) {
#pragma unroll
        for (int i = 0; i < 4; ++i)
            __hip_atomic_store(&part[bx * B_SZ + b0 + wv * 16 + quad * 4 + i],
                               rmax[i], __ATOMIC_RELAXED,
                               __HIP_MEMORY_SCOPE_AGENT);
    }
}

// ---------------------------------------------------------------------------
// K2: y->out copy (pure input) + reduce the 16 strip maxes (agent-scope
// atomic loads) into the last output column. Wave per row, 4 rows/block.
__global__ __launch_bounds__(256) void k_final(const float* __restrict__ y,
                                               float* __restrict__ part,
                                               float* __restrict__ out) {
    const int t = threadIdx.x;
    const int wv = t >> 6, lane = t & 63;
    const int b = blockIdx.x * 4 + wv;
    const float* yrow = y + b * C_SZ;
    float* orow = out + b * (C_SZ + 1);
#pragma unroll
    for (int i = 0; i < 4; ++i) {
        const int idx = i * 64 + lane;  // float4 index; 250 cover the row
        if (idx < 250)
            *(float4*)(orow + idx * 4) = *(const float4*)(yrow + idx * 4);
    }
    float m = -INFINITY;
    if (lane < 16)
        m = __hip_atomic_load(&part[lane * B_SZ + b], __ATOMIC_RELAXED,
                              __HIP_MEMORY_SCOPE_AGENT);
#pragma unroll
    for (int off = 8; off; off >>= 1) m = fmaxf(m, __shfl_xor(m, off, 64));
    if (lane == 0) orow[C_SZ] = m;
}

// ---------------------------------------------------------------------------
extern "C" void kernel_launch(void* const* d_in, const int* in_sizes, int n_in,
                              void* d_out, int out_size, void* d_ws,
                              size_t ws_size, hipStream_t stream) {
    const float* y = (const float*)d_in[0];
    const float* w = (const float*)d_in[1];
    const float* eps = (const float*)d_in[2];
    const float* lip = (const float*)d_in[3];
    float* out = (float*)d_out;
    float* part = (float*)d_ws;

    k_main<<<dim3(16, 16), 256, 0, stream>>>(y, w, eps, lip, part);
    k_final<<<B_SZ / 4, 256, 0, stream>>>(y, part, out);
}